// Round 7
// baseline (133.943 us; speedup 1.0000x reference)
//
#include <hip/hip_runtime.h>

#define C_IN   1024
#define C4     (C_IN / 4)      // 256 float4 per row (also C_out/4)
#define KCNT   256
#define TAU    0.05f           // split-bf16 score err ~4e-3 -> >10x margin
#define MB     16              // rows per block -> grid 1024
#define NCH    32              // K chunks of 32 dims

typedef __attribute__((ext_vector_type(8))) short bf16x8;
typedef __attribute__((ext_vector_type(4))) float f32x4;

static __device__ __forceinline__ unsigned short f2bf(float f) {
    union { float f; unsigned u; } v; v.f = f;
    unsigned r = v.u + 0x7fffu + ((v.u >> 16) & 1u);   // RNE
    return (unsigned short)(r >> 16);
}
static __device__ __forceinline__ float bf2f(unsigned short h) {
    union { unsigned u; float f; } v; v.u = (unsigned)h << 16;
    return v.f;
}
static __device__ __forceinline__ void cvt8(float4 a, float4 b,
                                            bf16x8& h8, bf16x8& l8) {
    float f[8] = {a.x, a.y, a.z, a.w, b.x, b.y, b.z, b.w};
#pragma unroll
    for (int i = 0; i < 8; ++i) {
        unsigned short hh = f2bf(f[i]);
        h8[i] = (short)hh;
        l8[i] = (short)f2bf(f[i] - bf2f(hh));   // exact residual
    }
}

// ---------------------------------------------------------------------------
// Prep (validated r6): keys -> 1 MB chunk-major hi/lo bf16 image:
// chunk c (32 KB) -> key-tile kt (2 KB) = [hi 1KB | lo 1KB], 1 KB lane-ordered:
// lane l = (key&15) + 16*(dim_in_chunk>>3), 16 B = 8 dims. k2[key] = ||key||^2.
// ---------------------------------------------------------------------------
__global__ __launch_bounds__(256) void prep_img(const float* __restrict__ keys,
        unsigned short* __restrict__ img, float* __restrict__ k2) {
    const int k = blockIdx.x, t = threadIdx.x;
    float4 v = ((const float4*)keys)[(size_t)k * C4 + t];
    float f[4] = {v.x, v.y, v.z, v.w};
    unsigned short h[4], lo[4];
#pragma unroll
    for (int i = 0; i < 4; ++i) {
        h[i]  = f2bf(f[i]);
        lo[i] = f2bf(f[i] - bf2f(h[i]));
    }
    const int c    = t >> 3;           // chunk = 4t/32
    const int dd   = (4 * t) & 31;     // dim-in-chunk
    const int lane = (k & 15) + ((dd >> 3) << 4);
    const size_t addr = (size_t)c * 32768 + (size_t)(k >> 4) * 2048
                      + (size_t)lane * 16 + (size_t)(dd & 7) * 2;
    *(ushort4*)((char*)img + addr)        = make_ushort4(h[0], h[1], h[2], h[3]);
    *(ushort4*)((char*)img + addr + 1024) = make_ushort4(lo[0], lo[1], lo[2], lo[3]);

    float s = f[0]*f[0] + f[1]*f[1] + f[2]*f[2] + f[3]*f[3];
#pragma unroll
    for (int off = 32; off; off >>= 1) s += __shfl_xor(s, off, 64);
    __shared__ float ws[4];
    if ((t & 63) == 0) ws[t >> 6] = s;
    __syncthreads();
    if (t == 0) k2[k] = ws[0] + ws[1] + ws[2] + ws[3];
}

// ---------------------------------------------------------------------------
// Main: block = 16 rows x 256 keys, 4 waves; wave w owns key-tiles 4w..4w+3.
// NO LDS in the hot loop (keys read straight from the L2-resident img, already
// bf16, 1KB coalesced per load); A global->reg with hi/lo split; 2-deep reg
// ring; sched_barrier(0) pins load issue ahead of compute; ZERO barriers
// before the epilogue. LDS ~2KB -> occupancy limited only by VGPR (~3 w/SIMD).
// mfma_f32_16x16x32_bf16, 3-product split (validated r3-r6, absmax 0).
// C layout: col(key)=lane&15, row=(lane>>4)*4+reg (validated).
// ---------------------------------------------------------------------------
__global__ __launch_bounds__(256, 3) void vq_stream(
        const float* __restrict__ x, const float* __restrict__ keys,
        const unsigned short* __restrict__ img,
        const float* __restrict__ k2g, const float* __restrict__ values,
        float* __restrict__ out) {
    __shared__ char smem[2048];

    const int t = threadIdx.x;
    const int w = t >> 6, l = t & 63;
    const int l15 = l & 15, lg = l >> 4;
    const int row0 = blockIdx.x * MB;

    f32x4 acch[4], accl[4];
#pragma unroll
    for (int j = 0; j < 4; ++j) {
        acch[j] = (f32x4){0.f, 0.f, 0.f, 0.f};
        accl[j] = (f32x4){0.f, 0.f, 0.f, 0.f};
    }

    // A: lane -> row l15, dims lg*8 + [0,8) per chunk
    const float* xr = x + (size_t)(row0 + l15) * C_IN + lg * 8;
    // B: wave's 4 key-tiles; lane's 16B slot within each 1KB fragment block
    const char* bsrc = (const char*)img + ((w * 4) << 11) + (l << 4);

    bf16x8 pB[8]; float4 pA0, pA1;
#pragma unroll
    for (int j = 0; j < 4; ++j) {
        pB[2 * j]     = *(const bf16x8*)(bsrc + (j << 11));
        pB[2 * j + 1] = *(const bf16x8*)(bsrc + (j << 11) + 1024);
    }
    pA0 = *(const float4*)xr;
    pA1 = *(const float4*)(xr + 4);

#pragma unroll 2
    for (int c = 0; c < NCH; ++c) {
        bf16x8 nB[8]; float4 nA0, nA1;
        if (c < NCH - 1) {
            const char* bs = bsrc + (size_t)(c + 1) * 32768;
#pragma unroll
            for (int j = 0; j < 4; ++j) {
                nB[2 * j]     = *(const bf16x8*)(bs + (j << 11));
                nB[2 * j + 1] = *(const bf16x8*)(bs + (j << 11) + 1024);
            }
            nA0 = *(const float4*)(xr + (c + 1) * 32);
            nA1 = *(const float4*)(xr + (c + 1) * 32 + 4);
        }
        __builtin_amdgcn_sched_barrier(0);   // loads stay issued above

        bf16x8 ah, al;
        cvt8(pA0, pA1, ah, al);
#pragma unroll
        for (int j = 0; j < 4; ++j) {
            acch[j] = __builtin_amdgcn_mfma_f32_16x16x32_bf16(ah, pB[2 * j],     acch[j], 0, 0, 0);
            accl[j] = __builtin_amdgcn_mfma_f32_16x16x32_bf16(ah, pB[2 * j + 1], accl[j], 0, 0, 0);
            accl[j] = __builtin_amdgcn_mfma_f32_16x16x32_bf16(al, pB[2 * j],     accl[j], 0, 0, 0);
        }
        if (c < NCH - 1) {
#pragma unroll
            for (int j = 0; j < 8; ++j) pB[j] = nB[j];
            pA0 = nA0; pA1 = nA1;
        }
    }

    // ---- epilogue
    float*  sv1  = (float*)smem;              // [4][16]
    float*  sv2  = (float*)(smem + 256);      // [4][16]
    int*    si1  = (int*)(smem + 512);        // [4][16]
    int*    sidx = (int*)(smem + 768);        // [16]
    float*  sgap = (float*)(smem + 832);      // [16]
    double* dva  = (double*)(smem + 896);     // [4]
    int*    dia  = (int*)(smem + 928);        // [4]

    float k2w[4];
#pragma unroll
    for (int j = 0; j < 4; ++j) k2w[j] = k2g[(w * 4 + j) * 16 + l15];

    // top-2 per row over the wave's 64 keys; 16-lane shuffle reduce
#pragma unroll
    for (int r = 0; r < 4; ++r) {
        float v1 = 1e30f, v2 = 1e30f; int i1 = 0;
#pragma unroll
        for (int j = 0; j < 4; ++j) {          // keys ascending in j
            float s = k2w[j] - 2.f * (acch[j][r] + accl[j][r]);
            if (s < v1) { v2 = v1; v1 = s; i1 = (w * 4 + j) * 16 + l15; }
            else        { v2 = fminf(v2, s); }
        }
#pragma unroll
        for (int off = 1; off < 16; off <<= 1) {
            float w1 = __shfl_xor(v1, off, 64);
            int   j1 = __shfl_xor(i1, off, 64);
            float w2 = __shfl_xor(v2, off, 64);
            if (w1 < v1 || (w1 == v1 && j1 < i1)) { v2 = fminf(v1, w2); v1 = w1; i1 = j1; }
            else                                  { v2 = fminf(v2, w1); }
        }
        if (l15 == 0) {
            const int row = lg * 4 + r;
            sv1[w * 16 + row] = v1; sv2[w * 16 + row] = v2; si1[w * 16 + row] = i1;
        }
    }
    __syncthreads();

    // cross-wave merge (idx tie-break)
    if (t < MB) {
        float v1 = sv1[t], v2 = sv2[t]; int i1 = si1[t];
#pragma unroll
        for (int ww = 1; ww < 4; ++ww) {
            float u1 = sv1[ww * 16 + t], u2 = sv2[ww * 16 + t];
            int   ui = si1[ww * 16 + t];
            if (u1 < v1 || (u1 == v1 && ui < i1)) { v2 = fminf(v1, u2); v1 = u1; i1 = ui; }
            else                                  { v2 = fminf(v2, u1); }
        }
        sidx[t] = i1; sgap[t] = v2 - v1;
    }
    __syncthreads();

    // fp64 refinement for near-tie rows (block-uniform branch; ~0.3% of rows)
    const float4* x4r = (const float4*)x;
    for (int fr = 0; fr < MB; ++fr) {
        if (sgap[fr] < TAU) {
            double dotd = 0.0, k2d = 0.0;
            const float4* xrr = x4r + (size_t)(row0 + fr) * C4;
            const float4* kr  = (const float4*)keys + (size_t)t * C4;
#pragma unroll 4
            for (int c4 = 0; c4 < C4; ++c4) {
                float4 xv = xrr[c4];
                float4 kv = kr[c4];
                dotd += (double)kv.x * (double)xv.x; k2d += (double)kv.x * (double)kv.x;
                dotd += (double)kv.y * (double)xv.y; k2d += (double)kv.y * (double)kv.y;
                dotd += (double)kv.z * (double)xv.z; k2d += (double)kv.z * (double)kv.z;
                dotd += (double)kv.w * (double)xv.w; k2d += (double)kv.w * (double)kv.w;
            }
            double sd = k2d - 2.0 * dotd;
            int    si = t;
#pragma unroll
            for (int off = 32; off; off >>= 1) {
                double od = __shfl_xor(sd, off, 64);
                int    oi = __shfl_xor(si, off, 64);
                if (od < sd || (od == sd && oi < si)) { sd = od; si = oi; }
            }
            if (l == 0) { dva[w] = sd; dia[w] = si; }
            __syncthreads();
            if (t == 0) {
                double b = dva[0]; int bi = dia[0];
#pragma unroll
                for (int ww = 1; ww < 4; ++ww)
                    if (dva[ww] < b || (dva[ww] == b && dia[ww] < bi)) { b = dva[ww]; bi = dia[ww]; }
                sidx[fr] = bi;
            }
            __syncthreads();
        }
    }

    // gather values rows -> out (coalesced, 4 KB/row)
    const float4* v4 = (const float4*)values;
    float4* o4 = (float4*)out;
#pragma unroll
    for (int r = 0; r < MB; ++r) {
        const int idx = sidx[r];
        o4[(size_t)(row0 + r) * C4 + t] = v4[(size_t)idx * C4 + t];
    }
}

// ---------------------------------------------------------------------------
// Fallback (no/small workspace): round-2 validated fp32 path.
// ---------------------------------------------------------------------------
#define FB_ROWS 16
__global__ __launch_bounds__(256) void codebook_fallback(
    const float* __restrict__ x, const float* __restrict__ keys,
    const float* __restrict__ values, float* __restrict__ out) {
    __shared__ float xs[FB_ROWS * C_IN];
    float4* xs4 = (float4*)xs;
    const int t = threadIdx.x;
    const int row0 = blockIdx.x * FB_ROWS;
    const float4* x4 = (const float4*)x;
#pragma unroll
    for (int i = 0; i < FB_ROWS; ++i)
        xs4[i * C4 + t] = x4[(size_t)row0 * C4 + i * C4 + t];
    __syncthreads();

    float acc[FB_ROWS];
#pragma unroll
    for (int r = 0; r < FB_ROWS; ++r) acc[r] = 0.f;
    float k2acc = 0.f;
    const float4* kptr = ((const float4*)keys) + (size_t)t * C4;
    for (int c4 = 0; c4 < C4; ++c4) {
        float4 kv = kptr[c4];
        k2acc += kv.x * kv.x + kv.y * kv.y + kv.z * kv.z + kv.w * kv.w;
#pragma unroll
        for (int r = 0; r < FB_ROWS; ++r) {
            float4 xv = xs4[r * C4 + c4];
            acc[r] = fmaf(kv.x, xv.x, acc[r]);
            acc[r] = fmaf(kv.y, xv.y, acc[r]);
            acc[r] = fmaf(kv.z, xv.z, acc[r]);
            acc[r] = fmaf(kv.w, xv.w, acc[r]);
        }
    }
    __syncthreads();
    float* ssc  = xs;
    int*   sidx = (int*)(xs + FB_ROWS * KCNT);
    float* sgap = xs + FB_ROWS * KCNT + FB_ROWS;
    double* dva = (double*)(xs + FB_ROWS * KCNT + 2 * FB_ROWS);
    int*    dia = (int*)(xs + FB_ROWS * KCNT + 2 * FB_ROWS + 8);
#pragma unroll
    for (int r = 0; r < FB_ROWS; ++r) ssc[r * KCNT + t] = k2acc - 2.f * acc[r];
    __syncthreads();
    const int wave = t >> 6, lane = t & 63;
#pragma unroll
    for (int i = 0; i < FB_ROWS / 4; ++i) {
        const int r = wave * (FB_ROWS / 4) + i;
        float v1 = ssc[r * KCNT + lane];
        int   i1 = lane;
        float v2 = 1e30f;
#pragma unroll
        for (int j = 1; j < 4; ++j) {
            float c = ssc[r * KCNT + lane + 64 * j];
            if (c < v1) { v2 = v1; v1 = c; i1 = lane + 64 * j; }
            else        { v2 = fminf(v2, c); }
        }
#pragma unroll
        for (int off = 32; off; off >>= 1) {
            float w1 = __shfl_xor(v1, off, 64);
            int   j1 = __shfl_xor(i1, off, 64);
            float w2 = __shfl_xor(v2, off, 64);
            if (w1 < v1 || (w1 == v1 && j1 < i1)) { v2 = fminf(v1, w2); v1 = w1; i1 = j1; }
            else                                  { v2 = fminf(v2, w1); }
        }
        if (lane == 0) { sidx[r] = i1; sgap[r] = v2 - v1; }
    }
    __syncthreads();
    for (int fr = 0; fr < FB_ROWS; ++fr) {
        if (sgap[fr] < 0.02f) {
            double dotd = 0.0, k2d = 0.0;
            const float4* xrow = x4 + (size_t)(row0 + fr) * C4;
#pragma unroll 4
            for (int c4 = 0; c4 < C4; ++c4) {
                float4 xv = xrow[c4];
                float4 kv = ((const float4*)keys)[(size_t)t * C4 + c4];
                dotd += (double)kv.x * (double)xv.x; k2d += (double)kv.x * (double)kv.x;
                dotd += (double)kv.y * (double)xv.y; k2d += (double)kv.y * (double)kv.y;
                dotd += (double)kv.z * (double)xv.z; k2d += (double)kv.z * (double)kv.z;
                dotd += (double)kv.w * (double)xv.w; k2d += (double)kv.w * (double)kv.w;
            }
            double sd = k2d - 2.0 * dotd;
            int    si = t;
#pragma unroll
            for (int off = 32; off; off >>= 1) {
                double od = __shfl_xor(sd, off, 64);
                int    oi = __shfl_xor(si, off, 64);
                if (od < sd || (od == sd && oi < si)) { sd = od; si = oi; }
            }
            if ((t & 63) == 0) { dva[wave] = sd; dia[wave] = si; }
            __syncthreads();
            if (t == 0) {
                double b = dva[0]; int bi = dia[0];
#pragma unroll
                for (int ww = 1; ww < 4; ++ww)
                    if (dva[ww] < b || (dva[ww] == b && dia[ww] < bi)) { b = dva[ww]; bi = dia[ww]; }
                sidx[fr] = bi;
            }
            __syncthreads();
        }
    }
    const float4* v4p = (const float4*)values;
    float4* o4 = (float4*)out;
#pragma unroll
    for (int r = 0; r < FB_ROWS; ++r) {
        const int idx = sidx[r];
        o4[(size_t)(row0 + r) * C4 + t] = v4p[(size_t)idx * C4 + t];
    }
}

extern "C" void kernel_launch(void* const* d_in, const int* in_sizes, int n_in,
                              void* d_out, int out_size, void* d_ws, size_t ws_size,
                              hipStream_t stream) {
    const float* x      = (const float*)d_in[0];
    const float* keys   = (const float*)d_in[1];
    const float* values = (const float*)d_in[2];
    float* out = (float*)d_out;

    const int nrows = in_sizes[0] / C_IN;  // 16384
    const size_t need = 1048576u + 1024u;  // img + k2

    if (d_ws != nullptr && ws_size >= need && (nrows % MB) == 0) {
        unsigned short* img = (unsigned short*)d_ws;
        float* k2 = (float*)((char*)d_ws + 1048576);
        prep_img<<<KCNT, 256, 0, stream>>>(keys, img, k2);
        vq_stream<<<nrows / MB, 256, 0, stream>>>(x, keys, img, k2, values, out);
    } else {
        codebook_fallback<<<nrows / FB_ROWS, 256, 0, stream>>>(x, keys, values, out);
    }
}